// Round 3
// baseline (250.767 us; speedup 1.0000x reference)
//
#include <hip/hip_runtime.h>

// STDP learner: tr_pre/tr_post elementwise + delta_w = 0.5*w*(conv-wgrad pair).
// delta_w[o,i,kh,kw] = 0.5*w[o,i,kh,kw] *
//   sum_{b,p,q} tpre[b,i,p+kh,q+kw]*out[b,o,p,q] - tpost[b,o,p,q]*in[b,i,p+kh,q+kw]
// Sizes: B=16 CIN=64 H=W=66 COUT=128 HO=WO=64 KH=KW=3
// out layout: [tr_pre 4460544][tr_post 8388608][delta_w 73728]
//
// R3: barrier-free k_mfma — fragments loaded global->VGPR directly (A-layout
// [m=lane&15][k=quad*8+j] => per-lane 16B contiguous, wave = 16 rows x 1 line),
// software-pipelined 1 half-step ahead. R2's DMA+barrier structure was
// latency-bound (1550 cyc/iter vs 300 compute). 3 dispatches total.

typedef unsigned short ushort_t;
typedef unsigned int uint_t;
typedef __attribute__((ext_vector_type(8))) short short8;
typedef __attribute__((ext_vector_type(4))) float floatx4;
typedef __attribute__((ext_vector_type(2))) float floatx2;

#define N_PRE   4460544      // 16*64*66*66
#define N_POST  8388608      // 16*128*64*64
#define N_DW    73728        // 128*64*9
#define O_TRPOST 4460544
#define O_DW     12849152
#define BSLICE   4325376     // per-kw shifted B copy: 16*64*66*64 elems

__device__ __forceinline__ ushort_t f2bf(float f) {
  uint_t u = __builtin_bit_cast(uint_t, f);
  u = (u + 0x7FFFu + ((u >> 16) & 1u)) >> 16;   // RNE
  return (ushort_t)u;
}

// ---- fused fill: [blocks 0..2112) pre+bfill, [2112..6208) post + A copies --
__global__ __launch_bounds__(256)
void k_fill(const float* __restrict__ in_sp, const float* __restrict__ out_sp,
            const float* __restrict__ tpre, const float* __restrict__ tpost,
            float* __restrict__ o_trpre, float* __restrict__ o_trpost,
            ushort_t* __restrict__ A1, ushort_t* __restrict__ A2,
            ushort_t* __restrict__ B1, ushort_t* __restrict__ B2, int use_ws) {
  int bx = blockIdx.x;
  if (bx < 2112) {
    // pre: thread = (row, q8), row = (b*64+i)*66+h over 67584 rows
    int tid = bx * 256 + threadIdx.x;                  // < 540672
    int row = tid >> 3, q8 = (tid & 7) * 8;
    int g = row * 66 + q8;                             // even -> 8B aligned
    float ftp[10], fin[10];
    #pragma unroll
    for (int k = 0; k < 5; ++k) {
      floatx2 a = *(const floatx2*)(tpre + g + 2 * k);
      floatx2 b = *(const floatx2*)(in_sp + g + 2 * k);
      ftp[2 * k] = a.x; ftp[2 * k + 1] = a.y;
      fin[2 * k] = b.x; fin[2 * k + 1] = b.y;
    }
    #pragma unroll
    for (int k = 0; k < 4; ++k) {
      floatx2 v = { 0.5f * ftp[2 * k] + fin[2 * k], 0.5f * ftp[2 * k + 1] + fin[2 * k + 1] };
      *(floatx2*)(o_trpre + g + 2 * k) = v;
    }
    if (q8 == 56) {                                    // tail cols 64,65
      floatx2 v = { 0.5f * ftp[8] + fin[8], 0.5f * ftp[9] + fin[9] };
      *(floatx2*)(o_trpre + row * 66 + 64) = v;
    }
    if (use_ws) {
      ushort_t utp[10], uin[10];
      #pragma unroll
      for (int k = 0; k < 10; ++k) { utp[k] = f2bf(ftp[k]); uin[k] = f2bf(fin[k]); }
      int dst = row * 64 + q8;                         // 16B aligned
      #pragma unroll
      for (int kw = 0; kw < 3; ++kw) {
        short8 v1, v2;
        #pragma unroll
        for (int k = 0; k < 8; ++k) { v1[k] = (short)utp[kw + k]; v2[k] = (short)uin[kw + k]; }
        *(short8*)(B1 + kw * BSLICE + dst) = v1;
        *(short8*)(B2 + kw * BSLICE + dst) = v2;
      }
    }
  } else {
    // post: elementwise tr_post + bf16 A copies
    int t8 = ((bx - 2112) * 256 + threadIdx.x) * 8;    // < N_POST
    floatx4 o0 = *(const floatx4*)(out_sp + t8);
    floatx4 o1 = *(const floatx4*)(out_sp + t8 + 4);
    floatx4 p0 = *(const floatx4*)(tpost + t8);
    floatx4 p1 = *(const floatx4*)(tpost + t8 + 4);
    *(floatx4*)(o_trpost + t8)     = 0.5f * p0 + o0;
    *(floatx4*)(o_trpost + t8 + 4) = 0.5f * p1 + o1;
    if (use_ws) {
      short8 va, vn;
      #pragma unroll
      for (int k = 0; k < 4; ++k) {
        va[k] = (short)f2bf(o0[k]); va[k + 4] = (short)f2bf(o1[k]);
        vn[k] = (short)f2bf(-p0[k]); vn[k + 4] = (short)f2bf(-p1[k]);
      }
      *(short8*)(A1 + t8) = va;
      *(short8*)(A2 + t8) = vn;
    }
  }
}

// ---- barrier-free MFMA split-K kernel --------------------------------------
// grid (64, 9): x = k-chunk (16 (b,p) rows), y = e = kh*3+kw.
// block 256 = 4 waves: wave w -> ksub = w>>1 (8-row half), oh = w&1 (o-half).
// Wave tile 64o x 64i, 16 accumulators; frags loaded straight from global.
// Half-step hs = rl*4 + ks*2 + mat  (rl = row-in-subchunk, ks = k32 half).
__global__ __launch_bounds__(256, 3)
void k_mfma(const ushort_t* __restrict__ A1, const ushort_t* __restrict__ A2,
            const ushort_t* __restrict__ B1, const ushort_t* __restrict__ B2,
            float* __restrict__ partials) {
  __shared__ float LRED[2][4096];                      // 32 KB epilogue reduce

  const int e = blockIdx.y, kh = e / 3, kw = e - kh * 3;
  const int bx = blockIdx.x;
  const int t = threadIdx.x, w = t >> 6, l = t & 63;
  const int ksub = w >> 1, oh = w & 1;
  const int quad = l >> 4, l16 = l & 15;
  const int b = bx >> 2;                               // const per block
  const int p0 = (bx & 3) * 16 + ksub * 8;             // no wrap over 8 rows

  const ushort_t* pa1 = A1 + (size_t)b * 524288 + p0 * 64;
  const ushort_t* pa2 = A2 + (size_t)b * 524288 + p0 * 64;
  const ushort_t* pb1 = B1 + kw * BSLICE + (size_t)b * 270336 + (p0 + kh) * 64;
  const ushort_t* pb2 = B2 + kw * BSLICE + (size_t)b * 270336 + (p0 + kh) * 64;

  int aoff[4], boff[4];
  #pragma unroll
  for (int mt = 0; mt < 4; ++mt) aoff[mt] = (oh * 64 + mt * 16 + l16) * 4096 + quad * 8;
  #pragma unroll
  for (int it = 0; it < 4; ++it) boff[it] = (it * 16 + l16) * 4224 + quad * 8;

  floatx4 acc[4][4] = {};
  short8 fa[4], fb[4], ga[4], gb[4];

  // prologue: hs=0 (rl=0, ks=0, mat=0)
  #pragma unroll
  for (int mt = 0; mt < 4; ++mt) fa[mt] = *(const short8*)(pa1 + aoff[mt]);
  #pragma unroll
  for (int it = 0; it < 4; ++it) fb[it] = *(const short8*)(pb1 + boff[it]);

  #pragma unroll
  for (int hs = 0; hs < 32; ++hs) {
    if (hs < 31) {                                     // prefetch hs+1
      const int nh = hs + 1;
      const int off = (nh >> 2) * 64 + ((nh >> 1) & 1) * 32;  // const after unroll
      const ushort_t* qa = (nh & 1) ? pa2 : pa1;
      const ushort_t* qb = (nh & 1) ? pb2 : pb1;
      #pragma unroll
      for (int mt = 0; mt < 4; ++mt) ga[mt] = *(const short8*)(qa + aoff[mt] + off);
      #pragma unroll
      for (int it = 0; it < 4; ++it) gb[it] = *(const short8*)(qb + boff[it] + off);
    }
    #pragma unroll
    for (int mt = 0; mt < 4; ++mt)
      #pragma unroll
      for (int it = 0; it < 4; ++it)
        acc[mt][it] = __builtin_amdgcn_mfma_f32_16x16x32_bf16(fa[mt], fb[it], acc[mt][it], 0, 0, 0);
    #pragma unroll
    for (int x = 0; x < 4; ++x) { fa[x] = ga[x]; fb[x] = gb[x]; }
  }

  // epilogue: ksub=1 waves dump to LDS; ksub=0 waves add + write partials.
  // C/D layout: col(i)=lane&15, row(o within 16)=quad*4+reg (HW-verified R1/R2)
  if (ksub == 1) {
    #pragma unroll
    for (int mt = 0; mt < 4; ++mt)
      #pragma unroll
      for (int it = 0; it < 4; ++it)
        #pragma unroll
        for (int rg = 0; rg < 4; ++rg)
          LRED[oh][(mt * 16 + quad * 4 + rg) * 64 + it * 16 + l16] = acc[mt][it][rg];
  }
  __syncthreads();
  if (ksub == 0) {
    float* slice = partials + (size_t)(e * 64 + bx) * 8192;
    #pragma unroll
    for (int mt = 0; mt < 4; ++mt)
      #pragma unroll
      for (int it = 0; it < 4; ++it)
        #pragma unroll
        for (int rg = 0; rg < 4; ++rg) {
          int ol = mt * 16 + quad * 4 + rg;
          int i = it * 16 + l16;
          slice[(oh * 64 + ol) * 64 + i] = acc[mt][it][rg] + LRED[oh][ol * 64 + i];
        }
  }
}

// ---- split-K reduction + finalize ------------------------------------------
__global__ void k_finalize(const float* __restrict__ partials,
                           const float* __restrict__ weight, float* __restrict__ dw) {
  int tid = blockIdx.x * 256 + threadIdx.x;            // < 73728
  int e = tid >> 13, oi = tid & 8191;
  float s = 0.f;
  #pragma unroll 8
  for (int c = 0; c < 64; ++c) s += partials[(size_t)(e * 64 + c) * 8192 + oi];
  int o = oi >> 6, i = oi & 63;
  int wi = (o * 64 + i) * 9 + e;
  dw[wi] = 0.5f * weight[wi] * s;
}

// ---- fallback (ws too small): slow fp32, zero scratch ----------------------
__global__ void k_naive(const float* __restrict__ out_sp, const float* __restrict__ tpost,
                        const float* __restrict__ tpre, const float* __restrict__ in_sp,
                        const float* __restrict__ weight, float* __restrict__ dw) {
  int tid = blockIdx.x * 256 + threadIdx.x;
  int e = tid >> 13, oi = tid & 8191;
  int o = oi >> 6, i = oi & 63;
  int kh = e / 3, kw = e - kh * 3;
  float acc = 0.f;
  for (int b = 0; b < 16; ++b)
    for (int p = 0; p < 64; ++p) {
      const float* ga = out_sp + ((b * 128 + o) * 64 + p) * 64;
      const float* gn = tpost + ((b * 128 + o) * 64 + p) * 64;
      const float* gb = tpre + ((b * 64 + i) * 66 + p + kh) * 66 + kw;
      const float* gm = in_sp + ((b * 64 + i) * 66 + p + kh) * 66 + kw;
      for (int q = 0; q < 64; ++q) acc += ga[q] * gb[q] - gn[q] * gm[q];
    }
  int wi = (o * 64 + i) * 9 + kh * 3 + kw;
  dw[wi] = 0.5f * weight[wi] * acc;
}

extern "C" void kernel_launch(void* const* d_in, const int* in_sizes, int n_in,
                              void* d_out, int out_size, void* d_ws, size_t ws_size,
                              hipStream_t stream) {
  const float* in_sp  = (const float*)d_in[0];
  const float* out_sp = (const float*)d_in[1];
  const float* tpre   = (const float*)d_in[2];
  const float* tpost  = (const float*)d_in[3];
  const float* weight = (const float*)d_in[4];
  float* out = (float*)d_out;
  float* o_trpre  = out;
  float* o_trpost = out + O_TRPOST;
  float* o_dw     = out + O_DW;

  // ws layout: A1 | A2 | B1(3 slices) | B2(3 slices) | partials(576*8192 f32)
  const size_t WS_NEED = 104333312;
  const int use_mfma = (ws_size >= WS_NEED) ? 1 : 0;
  ushort_t* A1 = (ushort_t*)d_ws;
  ushort_t* A2 = A1 + 8388608;
  ushort_t* B1 = A2 + 8388608;
  ushort_t* B2 = B1 + 3 * BSLICE;
  float* partials = (float*)(B2 + 3 * BSLICE);

  k_fill<<<6208, 256, 0, stream>>>(in_sp, out_sp, tpre, tpost,
                                   o_trpre, o_trpost, A1, A2, B1, B2, use_mfma);
  if (use_mfma) {
    dim3 g(64, 9);
    k_mfma<<<g, 256, 0, stream>>>(A1, A2, B1, B2, partials);
    k_finalize<<<N_DW / 256, 256, 0, stream>>>(partials, weight, o_dw);
  } else {
    k_naive<<<N_DW / 256, 256, 0, stream>>>(out_sp, tpost, tpre, in_sp, weight, o_dw);
  }
}